// Round 7
// baseline (400.286 us; speedup 1.0000x reference)
//
#include <hip/hip_runtime.h>
#include <math.h>

// Problem constants (fixed by setup_inputs): B=4, L=4096, k=16, PE_DIM=64.
// d_out is a FLOAT32 buffer (reference outputs are f32/int32); harness
// bf16-quantizes both sides for the absmax compare (established R0-R6).
namespace {
constexpr int BB  = 4;
constexpr int LL  = 4096;
constexpr int KK  = 16;
constexpr int NF  = 16;
constexpr int QPB = 32;            // queries per block (selection)
constexpr int SPL = 8;             // candidate splits per query
constexpr int CHK = LL / SPL;      // 512 candidates per thread

// flat f32 layout (element offsets), tuple return order:
// topk_indices [B,L,K], rpe [B,L,K,64], self_rpe [B,L,1,64],
// distances [B,L,K], neighbor_positions [B,L,K,2]
constexpr size_t N_IDX    = (size_t)BB * LL * KK;                 // 262144
constexpr size_t OFF_RPE  = N_IDX;                                // 262144
constexpr size_t OFF_SELF = OFF_RPE + N_IDX * 64;                 // 17039360
constexpr size_t OFF_DIST = OFF_SELF + (size_t)BB * LL * 64;      // 18087936
constexpr size_t OFF_NPOS = OFF_DIST + N_IDX;                     // 18350080
}

// round-to-nearest-even bf16, returned as f32 (matches ml_dtypes cast)
__device__ __forceinline__ float bf16r(float x) {
  unsigned u = __float_as_uint(x);
  unsigned r = (u + 0x7FFFu + ((u >> 16) & 1u)) & 0xFFFF0000u;
  return __uint_as_float(r);
}

// ---- Kernel S: k-NN top-16 selection; exact f32 indices -> chunk 0 ----
__global__ __launch_bounds__(256)
void sel_kernel(const float* __restrict__ positions,
                float* __restrict__ out)
{
  __shared__ unsigned long long smem[QPB][SPL][KK];   // 32 KB merge buffer

  const int tid  = threadIdx.x;
  const int b    = blockIdx.x >> 7;          // 128 blocks per batch
  const int brow = blockIdx.x & 127;
  const int q    = tid >> 3;                 // 0..31
  const int s    = tid & 7;                  // 0..7
  const int qrow = brow * QPB + q;
  const size_t gq = (size_t)b * LL + qrow;

  const float2* p2 = (const float2*)positions + (size_t)b * LL;
  const float2  P  = p2[qrow];

  // top-16 as monotone u64 keys: (f32 bits of d2)<<32 | idx.
  // d2 >= 0 so bit order == value order; ties -> lower idx first,
  // matching stable jax.lax.top_k on -d2.
  unsigned long long key[KK];
  #pragma unroll
  for (int j = 0; j < KK; ++j) key[j] = ~0ULL;

  for (int i = 0; i < CHK; ++i) {
    const int ci = s + i * SPL;              // ascending index order
    const float2 c = p2[ci];
    const float dx = c.x - P.x;
    const float dy = c.y - P.y;
    // XLA chain: rn(dx*dx) + rn(dy*dy), no fma contraction
    const float d2 = __fadd_rn(__fmul_rn(dx, dx), __fmul_rn(dy, dy));
    unsigned long long k2 =
        ((unsigned long long)__float_as_uint(d2) << 32) | (unsigned)ci;
    if (ci == qrow) k2 = ~0ULL;              // diagonal mask
    if (k2 < key[KK - 1]) {                  // strict <
      unsigned long long kj = k2;
      #pragma unroll
      for (int j = 0; j < KK; ++j) {         // predicated bubble, static idx
        const bool lt = kj < key[j];
        const unsigned long long nk = lt ? kj : key[j];
        const unsigned long long ok = lt ? key[j] : kj;
        key[j] = nk; kj = ok;
      }
    }
  }

  #pragma unroll
  for (int j = 0; j < KK; ++j) smem[q][s][j] = key[j];
  __syncthreads();

  if (s == 0) {                              // 8-way merge, single u64 compare
    int h[SPL];
    #pragma unroll
    for (int j = 0; j < SPL; ++j) h[j] = 0;
    #pragma unroll
    for (int r = 0; r < KK; ++r) {
      unsigned long long bk = ~0ULL; int bj = 0;
      #pragma unroll
      for (int j = 0; j < SPL; ++j) {
        const unsigned long long v = (h[j] < KK) ? smem[q][j][h[j]] : ~0ULL;
        const bool better = v < bk;
        bk = better ? v : bk;
        bj = better ? j : bj;
      }
      #pragma unroll
      for (int j = 0; j < SPL; ++j) h[j] += (j == bj) ? 1 : 0;
      const int ci = (int)(unsigned)(bk & 0xFFFFFFFFu);   // [0, 4095]
      out[gq * KK + r] = (float)ci;          // EXACT f32 (emit reads it back)
    }
  }
}

// ---- Kernel E: one thread per (query, neighbor); all other outputs ----
__global__ __launch_bounds__(256)
void emit_kernel(const float* __restrict__ positions,
                 float* __restrict__ out)
{
  const int gid = blockIdx.x * 256 + threadIdx.x;    // [0, 262144)
  const size_t g  = (size_t)gid;
  const size_t gq = g >> 4;
  const int b     = (int)(gq >> 12);
  const int qrow  = (int)(gq & 4095);

  const float2* p2 = (const float2*)positions + (size_t)b * LL;
  const int ci = (int)out[g];                // exact f32 idx from sel_kernel

  const float2 P = p2[qrow];
  const float2 c = p2[ci];
  const float dx = c.x - P.x;                // delta = neighbor - query
  const float dy = c.y - P.y;
  const float d2 = __fadd_rn(__fmul_rn(dx, dx), __fmul_rn(dy, dy));

  out[OFF_DIST + g] = bf16r(sqrtf(__fadd_rn(d2, 1e-8f)));
  {
    float2* np_ = (float2*)(out + OFF_NPOS) + g;
    *np_ = make_float2(bf16r(c.x), bf16r(c.y));
  }

  // physical_scale exactly as Python: 3.0 * sqrt(16/pi) in f64, then f32
  const float SCALE = (float)(3.0 * sqrt(16.0 / M_PI));
  const float PI_F  = (float)M_PI;           // freqs[f] = f32(pi) * 2^f exact
  const float tx = dx / SCALE;               // IEEE f32 div
  const float ty = dy / SCALE;

  float sxv[NF], cxv[NF], syv[NF], cyv[NF];
  #pragma unroll
  for (int f = 0; f < NF; ++f) {
    const float fr = PI_F * (float)(1 << f);
    sincosf(__fmul_rn(tx, fr), &sxv[f], &cxv[f]);   // accurate ocml sincos
    sincosf(__fmul_rn(ty, fr), &syv[f], &cyv[f]);
  }
  float4* rp = (float4*)(out + OFF_RPE + g * 64);
  #pragma unroll
  for (int w = 0; w < 4; ++w)
    rp[w]      = make_float4(bf16r(sxv[w*4]), bf16r(sxv[w*4+1]),
                             bf16r(sxv[w*4+2]), bf16r(sxv[w*4+3]));
  #pragma unroll
  for (int w = 0; w < 4; ++w)
    rp[4 + w]  = make_float4(bf16r(cxv[w*4]), bf16r(cxv[w*4+1]),
                             bf16r(cxv[w*4+2]), bf16r(cxv[w*4+3]));
  #pragma unroll
  for (int w = 0; w < 4; ++w)
    rp[8 + w]  = make_float4(bf16r(syv[w*4]), bf16r(syv[w*4+1]),
                             bf16r(syv[w*4+2]), bf16r(syv[w*4+3]));
  #pragma unroll
  for (int w = 0; w < 4; ++w)
    rp[12 + w] = make_float4(bf16r(cyv[w*4]), bf16r(cyv[w*4+1]),
                             bf16r(cyv[w*4+2]), bf16r(cyv[w*4+3]));

  // self_rpe: elements e = g*4 + [0..3]; value = bit4 of e = bit2 of g
  {
    const float v = ((g >> 2) & 1) ? 1.0f : 0.0f;
    float4* sp = (float4*)(out + OFF_SELF) + g;
    *sp = make_float4(v, v, v, v);
  }
}

extern "C" void kernel_launch(void* const* d_in, const int* in_sizes, int n_in,
                              void* d_out, int out_size, void* d_ws, size_t ws_size,
                              hipStream_t stream) {
  const float* positions = (const float*)d_in[0];
  float* out = (float*)d_out;

  sel_kernel <<<dim3(BB * (LL / QPB)), dim3(QPB * SPL), 0, stream>>>(positions, out);
  emit_kernel<<<dim3((int)(N_IDX / 256)),  dim3(256),   0, stream>>>(positions, out);
}

// Round 8
// 365.279 us; speedup vs baseline: 1.0958x; 1.0958x over previous
//
#include <hip/hip_runtime.h>
#include <math.h>

// Problem constants (fixed by setup_inputs): B=4, L=4096, k=16, PE_DIM=64.
// d_out is a FLOAT32 buffer; harness bf16-quantizes both sides for compare.
namespace {
constexpr int BB  = 4;
constexpr int LL  = 4096;
constexpr int KK  = 16;
constexpr int NF  = 16;
constexpr int QPB = 16;            // queries per block (selection)
constexpr int SPL = 16;            // candidate splits per query
constexpr int CHK = LL / SPL;      // 256 candidates per thread

// flat f32 layout (element offsets), tuple return order:
// topk_indices [B,L,K], rpe [B,L,K,64], self_rpe [B,L,1,64],
// distances [B,L,K], neighbor_positions [B,L,K,2]
constexpr size_t N_IDX    = (size_t)BB * LL * KK;                 // 262144
constexpr size_t OFF_RPE  = N_IDX;                                // 262144
constexpr size_t OFF_SELF = OFF_RPE + N_IDX * 64;                 // 17039360
constexpr size_t OFF_DIST = OFF_SELF + (size_t)BB * LL * 64;      // 18087936
constexpr size_t OFF_NPOS = OFF_DIST + N_IDX;                     // 18350080
}

// round-to-nearest-even bf16, returned as f32 (matches ml_dtypes cast)
__device__ __forceinline__ float bf16r(float x) {
  unsigned u = __float_as_uint(x);
  unsigned r = (u + 0x7FFFu + ((u >> 16) & 1u)) & 0xFFFF0000u;
  return __uint_as_float(r);
}

// ---- Kernel S: k-NN top-16 selection; exact f32 indices -> chunk 0 ----
// 1024 blocks x 256 threads: 16 queries/block x 16 splits (256 cand/thread).
__global__ __launch_bounds__(256)
void sel_kernel(const float* __restrict__ positions,
                float* __restrict__ out)
{
  __shared__ unsigned long long smem[QPB][SPL][KK];   // 32 KB merge buffer

  const int tid  = threadIdx.x;
  const int b    = blockIdx.x >> 8;          // 256 blocks per batch
  const int brow = blockIdx.x & 255;
  const int q    = tid >> 4;                 // 0..15 query-in-block
  const int s    = tid & 15;                 // 0..15 split
  const int qrow = brow * QPB + q;
  const size_t gq = (size_t)b * LL + qrow;

  const float2* p2 = (const float2*)positions + (size_t)b * LL;
  const float2  P  = p2[qrow];

  // top-16 as monotone u64 keys: (f32 bits of d2)<<32 | idx.
  // d2 >= 0 so bit order == value order; ties -> lower idx first,
  // matching stable jax.lax.top_k on -d2.
  unsigned long long key[KK];
  #pragma unroll
  for (int j = 0; j < KK; ++j) key[j] = ~0ULL;
  unsigned dmax_bits = 0xFFFFFFFFu;          // hi32 of key[15]

  for (int i = 0; i < CHK; ++i) {
    const int ci = s + i * SPL;              // ascending index order
    const float2 c = p2[ci];
    const float dx = c.x - P.x;
    const float dy = c.y - P.y;
    // XLA chain: rn(dx*dx) + rn(dy*dy), no fma contraction
    const float d2 = __fadd_rn(__fmul_rn(dx, dx), __fmul_rn(dy, dy));
    const unsigned d2b = __float_as_uint(d2);
    // u32-bits prefilter (valid: d2 >= 0). Equal-d2 reject is consistent:
    // within-thread scan is ascending idx, so equal-d2 later idx loses anyway.
    if (d2b < dmax_bits && ci != qrow) {
      unsigned long long kj = ((unsigned long long)d2b << 32) | (unsigned)ci;
      #pragma unroll
      for (int j = 0; j < KK; ++j) {         // predicated bubble, static idx
        const bool lt = kj < key[j];
        const unsigned long long nk = lt ? kj : key[j];
        const unsigned long long ok = lt ? key[j] : kj;
        key[j] = nk; kj = ok;
      }
      dmax_bits = (unsigned)(key[KK - 1] >> 32);
    }
  }

  #pragma unroll
  for (int j = 0; j < KK; ++j) smem[q][s][j] = key[j];
  __syncthreads();

  if (s == 0) {                              // 16-way merge, single u64 compare
    int h[SPL];
    #pragma unroll
    for (int j = 0; j < SPL; ++j) h[j] = 0;
    #pragma unroll
    for (int r = 0; r < KK; ++r) {
      unsigned long long bk = ~0ULL; int bj = 0;
      #pragma unroll
      for (int j = 0; j < SPL; ++j) {
        const unsigned long long v = (h[j] < KK) ? smem[q][j][h[j]] : ~0ULL;
        const bool better = v < bk;
        bk = better ? v : bk;
        bj = better ? j : bj;
      }
      #pragma unroll
      for (int j = 0; j < SPL; ++j) h[j] += (j == bj) ? 1 : 0;
      const int ci = (int)(unsigned)(bk & 0xFFFFFFFFu);   // [0, 4095]
      out[gq * KK + r] = (float)ci;          // EXACT f32 (emit reads it back)
    }
  }
}

// ---- Kernel E: one thread per (query, neighbor); all other outputs ----
__global__ __launch_bounds__(256)
void emit_kernel(const float* __restrict__ positions,
                 float* __restrict__ out)
{
  const int gid = blockIdx.x * 256 + threadIdx.x;    // [0, 262144)
  const size_t g  = (size_t)gid;
  const size_t gq = g >> 4;
  const int b     = (int)(gq >> 12);
  const int qrow  = (int)(gq & 4095);

  const float2* p2 = (const float2*)positions + (size_t)b * LL;
  const int ci = (int)out[g];                // exact f32 idx from sel_kernel

  const float2 P = p2[qrow];
  const float2 c = p2[ci];
  const float dx = c.x - P.x;                // delta = neighbor - query
  const float dy = c.y - P.y;
  const float d2 = __fadd_rn(__fmul_rn(dx, dx), __fmul_rn(dy, dy));

  out[OFF_DIST + g] = bf16r(sqrtf(__fadd_rn(d2, 1e-8f)));
  {
    float2* np_ = (float2*)(out + OFF_NPOS) + g;
    *np_ = make_float2(bf16r(c.x), bf16r(c.y));
  }

  // physical_scale exactly as Python: 3.0 * sqrt(16/pi) in f64, then f32
  const float SCALE = (float)(3.0 * sqrt(16.0 / M_PI));
  const float PI_F  = (float)M_PI;           // freqs[f] = f32(pi) * 2^f exact
  const float tx = dx / SCALE;               // IEEE f32 div
  const float ty = dy / SCALE;

  float sxv[NF], cxv[NF], syv[NF], cyv[NF];
  #pragma unroll
  for (int f = 0; f < NF; ++f) {
    const float fr = PI_F * (float)(1 << f);
    sincosf(__fmul_rn(tx, fr), &sxv[f], &cxv[f]);   // accurate ocml sincos
    sincosf(__fmul_rn(ty, fr), &syv[f], &cyv[f]);
  }
  float4* rp = (float4*)(out + OFF_RPE + g * 64);
  #pragma unroll
  for (int w = 0; w < 4; ++w)
    rp[w]      = make_float4(bf16r(sxv[w*4]), bf16r(sxv[w*4+1]),
                             bf16r(sxv[w*4+2]), bf16r(sxv[w*4+3]));
  #pragma unroll
  for (int w = 0; w < 4; ++w)
    rp[4 + w]  = make_float4(bf16r(cxv[w*4]), bf16r(cxv[w*4+1]),
                             bf16r(cxv[w*4+2]), bf16r(cxv[w*4+3]));
  #pragma unroll
  for (int w = 0; w < 4; ++w)
    rp[8 + w]  = make_float4(bf16r(syv[w*4]), bf16r(syv[w*4+1]),
                             bf16r(syv[w*4+2]), bf16r(syv[w*4+3]));
  #pragma unroll
  for (int w = 0; w < 4; ++w)
    rp[12 + w] = make_float4(bf16r(cyv[w*4]), bf16r(cyv[w*4+1]),
                             bf16r(cyv[w*4+2]), bf16r(cyv[w*4+3]));

  // self_rpe: elements e = g*4 + [0..3]; value = bit4 of e = bit2 of g
  {
    const float v = ((g >> 2) & 1) ? 1.0f : 0.0f;
    float4* sp = (float4*)(out + OFF_SELF) + g;
    *sp = make_float4(v, v, v, v);
  }
}

extern "C" void kernel_launch(void* const* d_in, const int* in_sizes, int n_in,
                              void* d_out, int out_size, void* d_ws, size_t ws_size,
                              hipStream_t stream) {
  const float* positions = (const float*)d_in[0];
  float* out = (float*)d_out;

  // 4 batches x 256 blocks (16 queries each) = 1024 blocks
  sel_kernel <<<dim3(BB * (LL / QPB)), dim3(QPB * SPL), 0, stream>>>(positions, out);
  emit_kernel<<<dim3((int)(N_IDX / 256)),  dim3(256),   0, stream>>>(positions, out);
}

// Round 9
// 308.368 us; speedup vs baseline: 1.2981x; 1.1846x over previous
//
#include <hip/hip_runtime.h>
#include <math.h>

// Problem constants (fixed by setup_inputs): B=4, L=4096, k=16, PE_DIM=64.
// d_out is a FLOAT32 buffer; harness bf16-quantizes both sides for compare.
namespace {
constexpr int BB  = 4;
constexpr int LL  = 4096;
constexpr int KK  = 16;
constexpr int NF  = 16;
constexpr int QPB = 16;            // queries per block (selection)
constexpr int SPL = 16;            // candidate splits per query
constexpr int CHK = LL / SPL;      // 256 candidates per thread
constexpr int CAP = 192;           // survivor cap per query

// flat f32 layout (element offsets), tuple return order:
// topk_indices [B,L,K], rpe [B,L,K,64], self_rpe [B,L,1,64],
// distances [B,L,K], neighbor_positions [B,L,K,2]
constexpr size_t N_IDX    = (size_t)BB * LL * KK;                 // 262144
constexpr size_t OFF_RPE  = N_IDX;                                // 262144
constexpr size_t OFF_SELF = OFF_RPE + N_IDX * 64;                 // 17039360
constexpr size_t OFF_DIST = OFF_SELF + (size_t)BB * LL * 64;      // 18087936
constexpr size_t OFF_NPOS = OFF_DIST + N_IDX;                     // 18350080
}

// round-to-nearest-even bf16, returned as f32 (matches ml_dtypes cast)
__device__ __forceinline__ float bf16r(float x) {
  unsigned u = __float_as_uint(x);
  unsigned r = (u + 0x7FFFu + ((u >> 16) & 1u)) & 0xFFFF0000u;
  return __uint_as_float(r);
}

// ---- Kernel S: count -> filter/compact -> exact select (+ exact fallback) ----
// 1024 blocks x 256 threads: 16 queries/block x 16 splits (256 cand/thread).
__global__ __launch_bounds__(256)
void sel2_kernel(const float* __restrict__ positions,
                 float* __restrict__ out)
{
  __shared__ unsigned long long surv[QPB][CAP + 1];   // ~24.7 KB (pad: banks)
  __shared__ unsigned int counts[QPB][SPL][4];        // 4 KB ladder counts
  __shared__ unsigned int red[QPB][4];
  __shared__ float        tb[QPB];                    // per-query tau0
  __shared__ float        tauq[QPB];                  // chosen tau (-1 = fallback)
  __shared__ unsigned int scnt[QPB];                  // survivor counters
  __shared__ unsigned int flags;                      // fallback bitmask

  const int tid  = threadIdx.x;
  const int b    = blockIdx.x >> 8;          // 256 blocks per batch
  const int brow = blockIdx.x & 255;
  const int q    = tid >> 4;                 // 0..15 query-in-block
  const int s    = tid & 15;                 // 0..15 split (low bits: line-coherent loads)
  const int qrow = brow * QPB + q;

  const float2* p2 = (const float2*)positions + (size_t)b * LL;
  const float2  P  = p2[qrow];

  if (tid == 0) flags = 0u;
  if (tid < QPB) scnt[tid] = 0u;

  // tau ladder seed: 2 * (32*sigma^2/L) * exp(|p|^2/(2 sigma^2)), sigma=50.
  // Heuristic only — count-verify below makes correctness independent of it.
  const float r2 = __fadd_rn(__fmul_rn(P.x, P.x), __fmul_rn(P.y, P.y));
  const float t0 = fminf(39.0625f * __expf(r2 * 2.0e-4f), 1000.0f);
  const float t1 = t0 * 4.0f, t2 = t0 * 16.0f, t3 = t0 * 64.0f;
  if (s == 0) tb[q] = t0;

  // ---- pass 1: exact ladder counts (XLA-exact distance chain) ----
  unsigned c0 = 0, c1 = 0, c2 = 0, c3 = 0;
  for (int i = 0; i < CHK; ++i) {
    const int ci = s + i * SPL;
    const float2 c = p2[ci];
    const float dx = c.x - P.x;
    const float dy = c.y - P.y;
    const float d2 = __fadd_rn(__fmul_rn(dx, dx), __fmul_rn(dy, dy));
    if (ci != qrow) {
      c0 += (d2 <= t0); c1 += (d2 <= t1); c2 += (d2 <= t2); c3 += (d2 <= t3);
    }
  }
  counts[q][s][0] = c0; counts[q][s][1] = c1;
  counts[q][s][2] = c2; counts[q][s][3] = c3;
  __syncthreads();

  if (tid < QPB * 4) {                       // reduce over splits
    const int qq = tid >> 2, jj = tid & 3;
    unsigned sum = 0;
    #pragma unroll
    for (int ss = 0; ss < SPL; ++ss) sum += counts[qq][ss][jj];
    red[qq][jj] = sum;
  }
  __syncthreads();

  if (tid < QPB) {                           // choose smallest tau with cnt>=16
    const unsigned n0 = red[tid][0], n1 = red[tid][1];
    const unsigned n2 = red[tid][2], n3 = red[tid][3];
    const float bt = tb[tid];
    float tc; unsigned nch;
    if      (n0 >= 16u) { tc = bt;          nch = n0; }
    else if (n1 >= 16u) { tc = bt * 4.0f;   nch = n1; }
    else if (n2 >= 16u) { tc = bt * 16.0f;  nch = n2; }
    else                { tc = bt * 64.0f;  nch = n3; }
    if (nch > (unsigned)CAP || n3 < 16u) {   // overflow/underflow -> exact fallback
      tc = -1.0f;
      atomicOr(&flags, 1u << tid);
    }
    tauq[tid] = tc;
  }
  __syncthreads();

  // ---- pass 2: filter + compact survivors into LDS ----
  const float tq = tauq[q];
  for (int i = 0; i < CHK; ++i) {
    const int ci = s + i * SPL;
    const float2 c = p2[ci];
    const float dx = c.x - P.x;
    const float dy = c.y - P.y;
    const float d2 = __fadd_rn(__fmul_rn(dx, dx), __fmul_rn(dy, dy));
    if (d2 <= tq && ci != qrow) {
      const unsigned slot = atomicAdd(&scnt[q], 1u);
      if (slot < (unsigned)CAP)
        surv[q][slot] =
            ((unsigned long long)__float_as_uint(d2) << 32) | (unsigned)ci;
    }
  }
  __syncthreads();

  // ---- pass 3: lane-per-query exact top-16 over survivors ----
  const unsigned fl = flags;
  if (tid < QPB && !((fl >> tid) & 1u)) {
    const int n = (int)scnt[tid];            // == chosen count, <= CAP
    unsigned long long dk[KK];
    #pragma unroll
    for (int j = 0; j < KK; ++j) dk[j] = ~0ULL;
    for (int i = 0; i < n; ++i) {
      unsigned long long k = surv[tid][i];
      if (k < dk[KK - 1]) {
        #pragma unroll
        for (int j = 0; j < KK; ++j) {
          const bool lt = k < dk[j];
          const unsigned long long nk = lt ? k : dk[j];
          const unsigned long long ok = lt ? dk[j] : k;
          dk[j] = nk; k = ok;
        }
      }
    }
    const size_t g3 = (size_t)b * LL + brow * QPB + tid;
    #pragma unroll
    for (int r = 0; r < KK; ++r)
      out[g3 * KK + r] = (float)(unsigned)(dk[r] & 0xFFFFFFFFu);
  }

  // ---- pass 4: exact fallback (R8 structure) for flagged queries ----
  unsigned fb = fl;
  while (fb) {
    const int fq = __ffs(fb) - 1; fb &= fb - 1;
    __syncthreads();                         // surv rows free after pass 3
    const int fqrow = brow * QPB + fq;
    const float2 FP = p2[fqrow];
    unsigned long long* scratch = &surv[0][0];   // 256 u64 fits in 2 rows
    if (tid < 16) {
      unsigned long long key[KK];
      #pragma unroll
      for (int j = 0; j < KK; ++j) key[j] = ~0ULL;
      unsigned dmax = 0xFFFFFFFFu;
      for (int i = 0; i < 256; ++i) {
        const int ci = tid + i * 16;
        const float2 c = p2[ci];
        const float dx = c.x - FP.x;
        const float dy = c.y - FP.y;
        const float d2 = __fadd_rn(__fmul_rn(dx, dx), __fmul_rn(dy, dy));
        const unsigned d2b = __float_as_uint(d2);
        if (d2b < dmax && ci != fqrow) {
          unsigned long long kj =
              ((unsigned long long)d2b << 32) | (unsigned)ci;
          #pragma unroll
          for (int j = 0; j < KK; ++j) {
            const bool lt = kj < key[j];
            const unsigned long long nk = lt ? kj : key[j];
            const unsigned long long ok = lt ? key[j] : kj;
            key[j] = nk; kj = ok;
          }
          dmax = (unsigned)(key[KK - 1] >> 32);
        }
      }
      #pragma unroll
      for (int j = 0; j < KK; ++j) scratch[tid * KK + j] = key[j];
    }
    __syncthreads();
    if (tid == 0) {                          // 16-way merge (R8 merge code)
      int h[16];
      #pragma unroll
      for (int j = 0; j < 16; ++j) h[j] = 0;
      const size_t gf = (size_t)b * LL + fqrow;
      #pragma unroll
      for (int r = 0; r < KK; ++r) {
        unsigned long long bk = ~0ULL; int bj = 0;
        #pragma unroll
        for (int j = 0; j < 16; ++j) {
          const unsigned long long v = (h[j] < KK) ? scratch[j * KK + h[j]] : ~0ULL;
          const bool better = v < bk;
          bk = better ? v : bk;
          bj = better ? j : bj;
        }
        #pragma unroll
        for (int j = 0; j < 16; ++j) h[j] += (j == bj) ? 1 : 0;
        out[gf * KK + r] = (float)(unsigned)(bk & 0xFFFFFFFFu);
      }
    }
  }
}

// ---- Kernel E: one thread per (query, neighbor); all other outputs ----
__global__ __launch_bounds__(256)
void emit_kernel(const float* __restrict__ positions,
                 float* __restrict__ out)
{
  const int gid = blockIdx.x * 256 + threadIdx.x;    // [0, 262144)
  const size_t g  = (size_t)gid;
  const size_t gq = g >> 4;
  const int b     = (int)(gq >> 12);
  const int qrow  = (int)(gq & 4095);

  const float2* p2 = (const float2*)positions + (size_t)b * LL;
  const int ci = (int)out[g];                // exact f32 idx from sel2_kernel

  const float2 P = p2[qrow];
  const float2 c = p2[ci];
  const float dx = c.x - P.x;                // delta = neighbor - query
  const float dy = c.y - P.y;
  const float d2 = __fadd_rn(__fmul_rn(dx, dx), __fmul_rn(dy, dy));

  out[OFF_DIST + g] = bf16r(sqrtf(__fadd_rn(d2, 1e-8f)));
  {
    float2* np_ = (float2*)(out + OFF_NPOS) + g;
    *np_ = make_float2(bf16r(c.x), bf16r(c.y));
  }

  // physical_scale exactly as Python: 3.0 * sqrt(16/pi) in f64, then f32
  const float SCALE = (float)(3.0 * sqrt(16.0 / M_PI));
  const float PI_F  = (float)M_PI;           // freqs[f] = f32(pi) * 2^f exact
  const float tx = dx / SCALE;               // IEEE f32 div
  const float ty = dy / SCALE;

  float sxv[NF], cxv[NF], syv[NF], cyv[NF];
  #pragma unroll
  for (int f = 0; f < NF; ++f) {
    const float fr = PI_F * (float)(1 << f);
    sincosf(__fmul_rn(tx, fr), &sxv[f], &cxv[f]);   // accurate ocml sincos
    sincosf(__fmul_rn(ty, fr), &syv[f], &cyv[f]);
  }
  float4* rp = (float4*)(out + OFF_RPE + g * 64);
  #pragma unroll
  for (int w = 0; w < 4; ++w)
    rp[w]      = make_float4(bf16r(sxv[w*4]), bf16r(sxv[w*4+1]),
                             bf16r(sxv[w*4+2]), bf16r(sxv[w*4+3]));
  #pragma unroll
  for (int w = 0; w < 4; ++w)
    rp[4 + w]  = make_float4(bf16r(cxv[w*4]), bf16r(cxv[w*4+1]),
                             bf16r(cxv[w*4+2]), bf16r(cxv[w*4+3]));
  #pragma unroll
  for (int w = 0; w < 4; ++w)
    rp[8 + w]  = make_float4(bf16r(syv[w*4]), bf16r(syv[w*4+1]),
                             bf16r(syv[w*4+2]), bf16r(syv[w*4+3]));
  #pragma unroll
  for (int w = 0; w < 4; ++w)
    rp[12 + w] = make_float4(bf16r(cyv[w*4]), bf16r(cyv[w*4+1]),
                             bf16r(cyv[w*4+2]), bf16r(cyv[w*4+3]));

  // self_rpe: elements e = g*4 + [0..3]; value = bit4 of e = bit2 of g
  {
    const float v = ((g >> 2) & 1) ? 1.0f : 0.0f;
    float4* sp = (float4*)(out + OFF_SELF) + g;
    *sp = make_float4(v, v, v, v);
  }
}

extern "C" void kernel_launch(void* const* d_in, const int* in_sizes, int n_in,
                              void* d_out, int out_size, void* d_ws, size_t ws_size,
                              hipStream_t stream) {
  const float* positions = (const float*)d_in[0];
  float* out = (float*)d_out;

  // 4 batches x 256 blocks (16 queries each) = 1024 blocks
  sel2_kernel<<<dim3(BB * (LL / QPB)), dim3(QPB * SPL), 0, stream>>>(positions, out);
  emit_kernel<<<dim3((int)(N_IDX / 256)),  dim3(256),   0, stream>>>(positions, out);
}

// Round 10
// 242.660 us; speedup vs baseline: 1.6496x; 1.2708x over previous
//
#include <hip/hip_runtime.h>
#include <math.h>

// Problem constants (fixed by setup_inputs): B=4, L=4096, k=16, PE_DIM=64.
// d_out is a FLOAT32 buffer; harness bf16-quantizes both sides for compare.
namespace {
constexpr int BB  = 4;
constexpr int LL  = 4096;
constexpr int KK  = 16;
constexpr int NF  = 16;
constexpr int QPB = 8;             // queries per block
constexpr int SPL = 32;            // candidate splits per query
constexpr int ITER = LL / (SPL * 2);   // 64 float4 iterations (2 points each)
constexpr int CAP = 192;           // survivor cap per query

// flat f32 layout (element offsets), tuple return order:
// topk_indices [B,L,K], rpe [B,L,K,64], self_rpe [B,L,1,64],
// distances [B,L,K], neighbor_positions [B,L,K,2]
constexpr size_t N_IDX    = (size_t)BB * LL * KK;                 // 262144
constexpr size_t OFF_RPE  = N_IDX;                                // 262144
constexpr size_t OFF_SELF = OFF_RPE + N_IDX * 64;                 // 17039360
constexpr size_t OFF_DIST = OFF_SELF + (size_t)BB * LL * 64;      // 18087936
constexpr size_t OFF_NPOS = OFF_DIST + N_IDX;                     // 18350080
}

// round-to-nearest-even bf16, returned as f32 (matches ml_dtypes cast)
__device__ __forceinline__ float bf16r(float x) {
  unsigned u = __float_as_uint(x);
  unsigned r = (u + 0x7FFFu + ((u >> 16) & 1u)) & 0xFFFF0000u;
  return __uint_as_float(r);
}

// XLA-exact squared distance: rn(dx*dx) + rn(dy*dy), no fma contraction
__device__ __forceinline__ float d2_of(float cx, float cy, float px, float py) {
  const float dx = cx - px, dy = cy - py;
  return __fadd_rn(__fmul_rn(dx, dx), __fmul_rn(dy, dy));
}

// ---- Kernel S: single-scan filter/append + ladder count -> rank select ----
// 2048 blocks x 256 threads: 8 queries/block x 32 splits (64 f4 iters each).
__global__ __launch_bounds__(256)
void sel3_kernel(const float* __restrict__ positions,
                 float* __restrict__ out)
{
  __shared__ unsigned long long surv[QPB][CAP + 1];   // 12.4 KB survivors
  __shared__ unsigned int cnts[QPB][SPL][4];          // 4 KB ladder counts
  __shared__ unsigned int red[QPB][4];
  __shared__ float        tb[QPB];                    // per-query tau
  __shared__ float        taur[QPB];                  // rescan tau (0=none,-1=fb)
  __shared__ unsigned int scnt[QPB];                  // survivor counters
  __shared__ unsigned int flags;                      // fallback bitmask

  const int tid  = threadIdx.x;
  const int b    = blockIdx.x >> 9;          // 512 blocks per batch
  const int brow = blockIdx.x & 511;
  const int q    = tid >> 5;                 // 0..7 query-in-block
  const int s    = tid & 31;                 // 0..31 split (low bits: coalesced)
  const int qrow = brow * QPB + q;

  const float2* p2 = (const float2*)positions + (size_t)b * LL;
  const float4* p4 = (const float4*)p2;
  const float2  P  = p2[qrow];

  if (tid == 0) flags = 0u;
  if (tid < QPB) scnt[tid] = 0u;

  // analytic tau targeting E[cnt]=48 under N(0,50^2) density:
  // tau = 48*(2 sigma^2/L) * exp(|p|^2/(2 sigma^2)). Ladder verifies exactly.
  const float r2 = __fadd_rn(__fmul_rn(P.x, P.x), __fmul_rn(P.y, P.y));
  const float t1 = 58.59375f * __expf(r2 * 2.0e-4f);
  const float ta = t1 * 0.1f, tbv = t1 * 0.4f, t2 = t1 * 3.0f;
  if (s == 0) tb[q] = t1;
  __syncthreads();                           // scnt ready before atomics

  // ---- single scan: 4-level exact counts + append survivors at t1 ----
  unsigned ca = 0, cb = 0, cc = 0, cd = 0;
  for (int i = 0; i < ITER; ++i) {
    const int pi = i * SPL + s;              // float4 index (2 points)
    const float4 c4 = p4[pi];
    const int ci0 = pi * 2, ci1 = pi * 2 + 1;
    {
      const float d2 = d2_of(c4.x, c4.y, P.x, P.y);
      if (ci0 != qrow) {
        ca += (d2 <= ta); cb += (d2 <= tbv); cc += (d2 <= t1); cd += (d2 <= t2);
        if (d2 <= t1) {
          const unsigned slot = atomicAdd(&scnt[q], 1u);
          if (slot < (unsigned)CAP)
            surv[q][slot] =
                ((unsigned long long)__float_as_uint(d2) << 32) | (unsigned)ci0;
        }
      }
    }
    {
      const float d2 = d2_of(c4.z, c4.w, P.x, P.y);
      if (ci1 != qrow) {
        ca += (d2 <= ta); cb += (d2 <= tbv); cc += (d2 <= t1); cd += (d2 <= t2);
        if (d2 <= t1) {
          const unsigned slot = atomicAdd(&scnt[q], 1u);
          if (slot < (unsigned)CAP)
            surv[q][slot] =
                ((unsigned long long)__float_as_uint(d2) << 32) | (unsigned)ci1;
        }
      }
    }
  }
  cnts[q][s][0] = ca; cnts[q][s][1] = cb;
  cnts[q][s][2] = cc; cnts[q][s][3] = cd;
  __syncthreads();

  if (tid < QPB * 4) {                       // reduce ladder counts over splits
    const int qq = tid >> 2, m = tid & 3;
    unsigned sum = 0;
    #pragma unroll
    for (int ss = 0; ss < SPL; ++ss) sum += cnts[qq][ss][m];
    red[qq][m] = sum;
  }
  __syncthreads();

  if (tid < QPB) {                           // pick level with cnt in [16,192]
    const unsigned na = red[tid][0], nb = red[tid][1];
    const unsigned nc = red[tid][2], nd = red[tid][3];
    const float t = tb[tid];
    float tr;
    if      (nc >= 16u && nc <= (unsigned)CAP) tr = 0.0f;      // stored set ok
    else if (nd >= 16u && nd <= (unsigned)CAP) tr = t * 3.0f;  // rescan up
    else if (nb >= 16u && nb <= (unsigned)CAP) tr = t * 0.4f;  // rescan down
    else if (na >= 16u && na <= (unsigned)CAP) tr = t * 0.1f;
    else { tr = -1.0f; atomicOr(&flags, 1u << tid); }          // exact fallback
    taur[tid] = tr;
  }
  __syncthreads();

  // ---- rescan-append at the verified level (rare; per-query 32 lanes) ----
  const float tr = taur[q];
  if (tr > 0.0f) {
    if (s == 0) scnt[q] = 0u;   // same half-wave as appends: LDS program order
    for (int i = 0; i < ITER; ++i) {
      const int pi = i * SPL + s;
      const float4 c4 = p4[pi];
      const int ci0 = pi * 2, ci1 = pi * 2 + 1;
      {
        const float d2 = d2_of(c4.x, c4.y, P.x, P.y);
        if (d2 <= tr && ci0 != qrow) {
          const unsigned slot = atomicAdd(&scnt[q], 1u);
          if (slot < (unsigned)CAP)
            surv[q][slot] =
                ((unsigned long long)__float_as_uint(d2) << 32) | (unsigned)ci0;
        }
      }
      {
        const float d2 = d2_of(c4.z, c4.w, P.x, P.y);
        if (d2 <= tr && ci1 != qrow) {
          const unsigned slot = atomicAdd(&scnt[q], 1u);
          if (slot < (unsigned)CAP)
            surv[q][slot] =
                ((unsigned long long)__float_as_uint(d2) << 32) | (unsigned)ci1;
        }
      }
    }
  }
  __syncthreads();

  // ---- parallel rank-select: 16 lanes/query, exact rank by counting ----
  const unsigned fl = flags;
  if (tid < QPB * 16) {
    const int qq = tid >> 4, l = tid & 15;
    if (!((fl >> qq) & 1u)) {
      const int n = (int)scnt[qq];           // in [16, 192], complete set
      const size_t g3 = (size_t)b * LL + (size_t)brow * QPB + qq;
      for (int j = l; j < n; j += 16) {
        const unsigned long long k = surv[qq][j];
        int rank = 0;
        for (int j2 = 0; j2 < n; ++j2) rank += (surv[qq][j2] < k);
        if (rank < KK)
          out[g3 * KK + rank] = (float)(unsigned)(k & 0xFFFFFFFFu);
      }
    }
  }

  // ---- exact fallback for flagged queries (R9-proven structure) ----
  unsigned fb = fl;
  while (fb) {
    const int fq = __ffs(fb) - 1; fb &= fb - 1;
    __syncthreads();                         // surv rows free after rank-select
    const int fqrow = brow * QPB + fq;
    const float2 FP = p2[fqrow];
    unsigned long long* scratch = &surv[0][0];   // 256 u64
    if (tid < 16) {
      unsigned long long key[KK];
      #pragma unroll
      for (int j = 0; j < KK; ++j) key[j] = ~0ULL;
      unsigned dmax = 0xFFFFFFFFu;
      for (int i = 0; i < 256; ++i) {
        const int ci = tid + i * 16;
        const float d2 = d2_of(p2[ci].x, p2[ci].y, FP.x, FP.y);
        const unsigned d2b = __float_as_uint(d2);
        if (d2b < dmax && ci != fqrow) {
          unsigned long long kj =
              ((unsigned long long)d2b << 32) | (unsigned)ci;
          #pragma unroll
          for (int j = 0; j < KK; ++j) {
            const bool lt = kj < key[j];
            const unsigned long long nk = lt ? kj : key[j];
            const unsigned long long ok = lt ? key[j] : kj;
            key[j] = nk; kj = ok;
          }
          dmax = (unsigned)(key[KK - 1] >> 32);
        }
      }
      #pragma unroll
      for (int j = 0; j < KK; ++j) scratch[tid * KK + j] = key[j];
    }
    __syncthreads();
    if (tid == 0) {                          // 16-way merge
      int h[16];
      #pragma unroll
      for (int j = 0; j < 16; ++j) h[j] = 0;
      const size_t gf = (size_t)b * LL + fqrow;
      #pragma unroll
      for (int r = 0; r < KK; ++r) {
        unsigned long long bk = ~0ULL; int bj = 0;
        #pragma unroll
        for (int j = 0; j < 16; ++j) {
          const unsigned long long v = (h[j] < KK) ? scratch[j * KK + h[j]] : ~0ULL;
          const bool better = v < bk;
          bk = better ? v : bk;
          bj = better ? j : bj;
        }
        #pragma unroll
        for (int j = 0; j < 16; ++j) h[j] += (j == bj) ? 1 : 0;
        out[gf * KK + r] = (float)(unsigned)(bk & 0xFFFFFFFFu);
      }
    }
  }
}

// ---- Kernel E: one thread per (query, neighbor); all other outputs ----
__global__ __launch_bounds__(256)
void emit_kernel(const float* __restrict__ positions,
                 float* __restrict__ out)
{
  const int gid = blockIdx.x * 256 + threadIdx.x;    // [0, 262144)
  const size_t g  = (size_t)gid;
  const size_t gq = g >> 4;
  const int b     = (int)(gq >> 12);
  const int qrow  = (int)(gq & 4095);

  const float2* p2 = (const float2*)positions + (size_t)b * LL;
  const int ci = (int)out[g];                // exact f32 idx from sel3_kernel

  const float2 P = p2[qrow];
  const float2 c = p2[ci];
  const float dx = c.x - P.x;                // delta = neighbor - query
  const float dy = c.y - P.y;
  const float d2 = __fadd_rn(__fmul_rn(dx, dx), __fmul_rn(dy, dy));

  out[OFF_DIST + g] = bf16r(sqrtf(__fadd_rn(d2, 1e-8f)));
  {
    float2* np_ = (float2*)(out + OFF_NPOS) + g;
    *np_ = make_float2(bf16r(c.x), bf16r(c.y));
  }

  // physical_scale exactly as Python: 3.0 * sqrt(16/pi) in f64, then f32
  const float SCALE = (float)(3.0 * sqrt(16.0 / M_PI));
  const float PI_F  = (float)M_PI;           // freqs[f] = f32(pi) * 2^f exact
  const float tx = dx / SCALE;               // IEEE f32 div
  const float ty = dy / SCALE;

  float sxv[NF], cxv[NF], syv[NF], cyv[NF];
  #pragma unroll
  for (int f = 0; f < NF; ++f) {
    const float fr = PI_F * (float)(1 << f);
    sincosf(__fmul_rn(tx, fr), &sxv[f], &cxv[f]);   // accurate ocml sincos
    sincosf(__fmul_rn(ty, fr), &syv[f], &cyv[f]);
  }
  float4* rp = (float4*)(out + OFF_RPE + g * 64);
  #pragma unroll
  for (int w = 0; w < 4; ++w)
    rp[w]      = make_float4(bf16r(sxv[w*4]), bf16r(sxv[w*4+1]),
                             bf16r(sxv[w*4+2]), bf16r(sxv[w*4+3]));
  #pragma unroll
  for (int w = 0; w < 4; ++w)
    rp[4 + w]  = make_float4(bf16r(cxv[w*4]), bf16r(cxv[w*4+1]),
                             bf16r(cxv[w*4+2]), bf16r(cxv[w*4+3]));
  #pragma unroll
  for (int w = 0; w < 4; ++w)
    rp[8 + w]  = make_float4(bf16r(syv[w*4]), bf16r(syv[w*4+1]),
                             bf16r(syv[w*4+2]), bf16r(syv[w*4+3]));
  #pragma unroll
  for (int w = 0; w < 4; ++w)
    rp[12 + w] = make_float4(bf16r(cyv[w*4]), bf16r(cyv[w*4+1]),
                             bf16r(cyv[w*4+2]), bf16r(cyv[w*4+3]));

  // self_rpe: elements e = g*4 + [0..3]; value = bit4 of e = bit2 of g
  {
    const float v = ((g >> 2) & 1) ? 1.0f : 0.0f;
    float4* sp = (float4*)(out + OFF_SELF) + g;
    *sp = make_float4(v, v, v, v);
  }
}

extern "C" void kernel_launch(void* const* d_in, const int* in_sizes, int n_in,
                              void* d_out, int out_size, void* d_ws, size_t ws_size,
                              hipStream_t stream) {
  const float* positions = (const float*)d_in[0];
  float* out = (float*)d_out;

  // 4 batches x 512 blocks (8 queries each) = 2048 blocks
  sel3_kernel<<<dim3(BB * (LL / QPB)), dim3(QPB * SPL), 0, stream>>>(positions, out);
  emit_kernel<<<dim3((int)(N_IDX / 256)), dim3(256),    0, stream>>>(positions, out);
}